// Round 1
// baseline (1449.189 us; speedup 1.0000x reference)
//
#include <hip/hip_runtime.h>

typedef _Float16 half8 __attribute__((ext_vector_type(8)));
typedef _Float16 half4 __attribute__((ext_vector_type(4)));
typedef float f32x4 __attribute__((ext_vector_type(4)));

// ---------------- BN stats: mean/rstd per channel over (B=32, V=4000) ----------------
__global__ __launch_bounds__(256) void k_bn_stats(const float* __restrict__ x,
                                                  float* __restrict__ musig) {
  const int c = blockIdx.x;
  const int t = threadIdx.x;
  float s = 0.f, s2 = 0.f;
  for (int b = 0; b < 32; ++b) {
    const float* row = x + ((size_t)(b * 16 + c)) * 4000;
    for (int v = t; v < 4000; v += 256) {
      float val = row[v];
      s += val;
      s2 += val * val;
    }
  }
#pragma unroll
  for (int off = 32; off > 0; off >>= 1) {
    s += __shfl_down(s, off);
    s2 += __shfl_down(s2, off);
  }
  __shared__ float rs[4], rs2[4];
  const int w = t >> 6;
  if ((t & 63) == 0) { rs[w] = s; rs2[w] = s2; }
  __syncthreads();
  if (t == 0) {
    float S = rs[0] + rs[1] + rs[2] + rs[3];
    float S2 = rs2[0] + rs2[1] + rs2[2] + rs2[3];
    const float inv = 1.f / 128000.f;
    float mu = S * inv;
    float var = S2 * inv - mu * mu;
    musig[c] = mu;
    musig[16 + c] = rsqrtf(var + 1e-5f);
  }
}

// ---------------- build x0 (normalized, permuted, transposed, scaled 1/16) ----------------
// X0[m*4096 + v] = x0[v][m],  m = c*32+b
__global__ __launch_bounds__(256) void k_build_x0(const float* __restrict__ x,
                                                  const int* __restrict__ perm,
                                                  const float* __restrict__ musig,
                                                  _Float16* __restrict__ X0) {
  const int idx = blockIdx.x * 256 + threadIdx.x;  // < 512*4096
  const int v = idx & 4095;
  const int m = idx >> 12;
  const int b = m & 31;
  const int c = m >> 5;
  const int pv = perm[v];
  float val = 0.f;
  if (pv < 4000)
    val = (x[((size_t)(b * 16 + c)) * 4000 + pv] - musig[c]) * musig[16 + c] * 0.0625f;
  X0[idx] = (_Float16)val;
}

// ---------------- f32 -> f16 convert ----------------
__global__ __launch_bounds__(256) void k_cvt_f16(const float* __restrict__ s,
                                                 _Float16* __restrict__ d, int n) {
  const int i = (blockIdx.x * 256 + threadIdx.x) * 4;
  if (i >= n) return;
  f32x4 v = *(const f32x4*)(s + i);
  half4 h;
  h[0] = (_Float16)v[0]; h[1] = (_Float16)v[1];
  h[2] = (_Float16)v[2]; h[3] = (_Float16)v[3];
  *(half4*)(d + i) = h;
}

// ---------------- W permute+pad: Wp[f][k*CS + c] = W[f][c*25 + k], k<25 else 0 ----------------
__global__ __launch_bounds__(256) void k_prep_w(const float* __restrict__ W,
                                                _Float16* __restrict__ Wp,
                                                int F, int shiftC) {
  const int idx = blockIdx.x * 256 + threadIdx.x;
  const int CS = 1 << shiftC;
  const int KPtot = 26 * CS;
  if (idx >= F * KPtot) return;
  const int f = idx / KPtot;
  const int rem = idx - f * KPtot;
  const int k = rem >> shiftC;
  const int c = rem & (CS - 1);
  float v = 0.f;
  if (k < 25) v = W[(size_t)f * (CS * 25) + c * 25 + k];
  Wp[idx] = (_Float16)v;
}

// ---------------- Chebyshev step GEMM: Xout[m][v] = alpha*sum_u Xprev[m][u]*L[v][u] - beta*Xm2[m][v]
// Tile 64(m) x 64(v), BK=64, 4 waves each 32x32, dbuf LDS, XOR swizzle.
__global__ __launch_bounds__(256, 2) void k_cheb(const _Float16* __restrict__ Xprev,
                                                 const _Float16* __restrict__ Lm,
                                                 const _Float16* __restrict__ Xm2,
                                                 _Float16* __restrict__ Xout,
                                                 int V, float alpha, float beta) {
  __shared__ _Float16 lds[2][2][4096];  // [buf][A/B][64*64]
  const int t = threadIdx.x;
  const int lane = t & 63;
  const int w = t >> 6;
  const int wr = w >> 1, wc = w & 1;
  const int v0 = blockIdx.x * 64;
  const int m0 = blockIdx.y * 64;
  const size_t rs = (size_t)V * 2;  // row stride bytes (X' and L share V)

  const char* Ab = (const char*)Xprev + (size_t)m0 * rs;
  const char* Bb = (const char*)Lm + (size_t)v0 * rs;

  const int srow = t >> 3;          // 0..31
  const int scb = (t & 7) * 16;     // 0..112

  f32x4 acc00 = {0.f, 0.f, 0.f, 0.f}, acc01 = {0.f, 0.f, 0.f, 0.f};
  f32x4 acc10 = {0.f, 0.f, 0.f, 0.f}, acc11 = {0.f, 0.f, 0.f, 0.f};

  const int NT = V >> 6;
  half8 ra0, ra1, rb0, rb1;

  auto gload = [&](int tt) {
    const char* au = Ab + (size_t)tt * 128;
    const char* bu = Bb + (size_t)tt * 128;
    ra0 = *(const half8*)(au + (size_t)srow * rs + scb);
    ra1 = *(const half8*)(au + (size_t)(srow + 32) * rs + scb);
    rb0 = *(const half8*)(bu + (size_t)srow * rs + scb);
    rb1 = *(const half8*)(bu + (size_t)(srow + 32) * rs + scb);
  };
  auto dswrite = [&](int buf) {
    char* A = (char*)&lds[buf][0][0];
    char* B = (char*)&lds[buf][1][0];
    const int r0 = srow, r1 = srow + 32;
    *(half8*)(A + r0 * 128 + (scb ^ ((r0 & 7) << 4))) = ra0;
    *(half8*)(A + r1 * 128 + (scb ^ ((r1 & 7) << 4))) = ra1;
    *(half8*)(B + r0 * 128 + (scb ^ ((r0 & 7) << 4))) = rb0;
    *(half8*)(B + r1 * 128 + (scb ^ ((r1 & 7) << 4))) = rb1;
  };

  gload(0);
  dswrite(0);
  if (NT > 1) gload(1);
  __syncthreads();

  for (int tt = 0; tt < NT; ++tt) {
    const int cur = tt & 1;
    if (tt + 1 < NT) dswrite(cur ^ 1);
    if (tt + 2 < NT) gload(tt + 2);
    const char* A = (const char*)&lds[cur][0][0];
    const char* B = (const char*)&lds[cur][1][0];
#pragma unroll
    for (int kk = 0; kk < 2; ++kk) {
      const int cb = kk * 64 + ((lane >> 4) << 4);
      const int ar0 = (wr << 5) + (lane & 15);
      const int ar1 = ar0 + 16;
      const int br0 = (wc << 5) + (lane & 15);
      const int br1 = br0 + 16;
      half8 a0 = *(const half8*)(A + ar0 * 128 + (cb ^ ((ar0 & 7) << 4)));
      half8 a1 = *(const half8*)(A + ar1 * 128 + (cb ^ ((ar1 & 7) << 4)));
      half8 b0 = *(const half8*)(B + br0 * 128 + (cb ^ ((br0 & 7) << 4)));
      half8 b1 = *(const half8*)(B + br1 * 128 + (cb ^ ((br1 & 7) << 4)));
      acc00 = __builtin_amdgcn_mfma_f32_16x16x32_f16(a0, b0, acc00, 0, 0, 0);
      acc01 = __builtin_amdgcn_mfma_f32_16x16x32_f16(a0, b1, acc01, 0, 0, 0);
      acc10 = __builtin_amdgcn_mfma_f32_16x16x32_f16(a1, b0, acc10, 0, 0, 0);
      acc11 = __builtin_amdgcn_mfma_f32_16x16x32_f16(a1, b1, acc11, 0, 0, 0);
    }
    __syncthreads();
  }

  // epilogue: xk = alpha*acc - beta*xm2, store f16
  const int rbase = (lane >> 4) << 2;
#pragma unroll
  for (int mi = 0; mi < 2; ++mi) {
#pragma unroll
    for (int ni = 0; ni < 2; ++ni) {
      f32x4 a = (mi == 0) ? ((ni == 0) ? acc00 : acc01) : ((ni == 0) ? acc10 : acc11);
      const int vv = v0 + (wc << 5) + (ni << 4) + (lane & 15);
#pragma unroll
      for (int r = 0; r < 4; ++r) {
        const int mm = m0 + (wr << 5) + (mi << 4) + rbase + r;
        const size_t idx = (size_t)mm * V + vv;
        float val = alpha * a[r];
        if (beta != 0.f) val -= (float)Xm2[idx];
        Xout[idx] = (_Float16)val;
      }
    }
  }
}

// ---------------- Dense projection GEMM (64f x 64n tile), fused bias+relu ----------------
// Yt[f][n] = relu(ascale * sum_q Wp[f][q] * B[q][n] + bscale*bias[f]),
// B[q][n] = XS[k][c*32+b][v], q = k<<shiftC | c, n = b*Vv + v
__global__ __launch_bounds__(256, 2) void k_dense(const _Float16* __restrict__ Wp,
                                                  const _Float16* __restrict__ XS,
                                                  const float* __restrict__ bias,
                                                  float* __restrict__ Yt,
                                                  int Vv, int shiftC, int nsteps,
                                                  size_t planeV, int Ntot,
                                                  float ascale, float bscale) {
  __shared__ _Float16 Alds[64 * 32];
  __shared__ _Float16 Blds[32 * 64];
  const int t = threadIdx.x;
  const int lane = t & 63;
  const int w = t >> 6;
  const int n0 = blockIdx.x * 64;
  const int f0 = blockIdx.y * 64;
  const int b = n0 / Vv;
  const int vb = n0 % Vv;
  const int KP = nsteps * 32;
  const int cmask = (1 << shiftC) - 1;

  f32x4 acc0 = {0.f, 0.f, 0.f, 0.f}, acc1 = {0.f, 0.f, 0.f, 0.f};
  f32x4 acc2 = {0.f, 0.f, 0.f, 0.f}, acc3 = {0.f, 0.f, 0.f, 0.f};

  for (int s = 0; s < nsteps; ++s) {
    const int q0 = s * 32;
    {  // A stage: 64 rows x 64B
      const int row = t >> 2, cb = (t & 3) * 16;
      half8 v = *(const half8*)((const char*)Wp + ((size_t)(f0 + row) * KP + q0) * 2 + cb);
      *(half8*)((char*)Alds + row * 64 + cb) = v;
    }
    {  // B stage: 32 rows x 128B, zero-pad k>=25
      const int q = q0 + (t >> 3), cb = (t & 7) * 16;
      const int k = q >> shiftC, c = q & cmask;
      half8 v = {};
      if (k < 25)
        v = *(const half8*)((const char*)XS +
                            ((size_t)k * planeV + (size_t)(c * 32 + b) * Vv + vb) * 2 + cb);
      *(half8*)((char*)Blds + (t >> 3) * 128 + cb) = v;
    }
    __syncthreads();
    half8 a0 = *(const half8*)((char*)Alds + ((lane & 15) + 0) * 64 + ((lane >> 4) << 4));
    half8 a1 = *(const half8*)((char*)Alds + ((lane & 15) + 16) * 64 + ((lane >> 4) << 4));
    half8 a2 = *(const half8*)((char*)Alds + ((lane & 15) + 32) * 64 + ((lane >> 4) << 4));
    half8 a3 = *(const half8*)((char*)Alds + ((lane & 15) + 48) * 64 + ((lane >> 4) << 4));
    half8 bf;
    const int col = (w << 4) + (lane & 15);
#pragma unroll
    for (int j = 0; j < 8; ++j)
      bf[j] = Blds[(((lane >> 4) << 3) + j) * 64 + col];
    acc0 = __builtin_amdgcn_mfma_f32_16x16x32_f16(a0, bf, acc0, 0, 0, 0);
    acc1 = __builtin_amdgcn_mfma_f32_16x16x32_f16(a1, bf, acc1, 0, 0, 0);
    acc2 = __builtin_amdgcn_mfma_f32_16x16x32_f16(a2, bf, acc2, 0, 0, 0);
    acc3 = __builtin_amdgcn_mfma_f32_16x16x32_f16(a3, bf, acc3, 0, 0, 0);
    __syncthreads();
  }

  const int n = n0 + (w << 4) + (lane & 15);
  f32x4 accs[4] = {acc0, acc1, acc2, acc3};
#pragma unroll
  for (int mi = 0; mi < 4; ++mi) {
#pragma unroll
    for (int r = 0; r < 4; ++r) {
      const int f = f0 + (mi << 4) + ((lane >> 4) << 2) + r;
      float val = ascale * accs[mi][r] + bscale * bias[f];
      Yt[(size_t)f * Ntot + n] = fmaxf(val, 0.f);
    }
  }
}

// ---------------- pool1: Yt1(64 x 131072) -> XS plane0 (2048 x 1024), scale 1/64 ----------------
__global__ __launch_bounds__(256) void k_pool1(const float* __restrict__ Yt,
                                               _Float16* __restrict__ X2) {
  const int idx = blockIdx.x * 256 + threadIdx.x;  // < 64*32*1024
  const int v2 = idx & 1023;
  const int rest = idx >> 10;
  const int b = rest & 31;
  const int f = rest >> 5;
  f32x4 q = *(const f32x4*)(Yt + (size_t)f * 131072 + b * 4096 + v2 * 4);
  float mx = fmaxf(fmaxf(q[0], q[1]), fmaxf(q[2], q[3]));
  X2[(size_t)(f * 32 + b) * 1024 + v2] = (_Float16)(mx * 0.015625f);
}

// ---------------- pool2: Yt2(128 x 32768) -> p2[b][f][v3] (32 x 128 x 256) ----------------
__global__ __launch_bounds__(256) void k_pool2(const float* __restrict__ Yt,
                                               float* __restrict__ p2) {
  const int idx = blockIdx.x * 256 + threadIdx.x;  // < 32*128*256
  const int v3 = idx & 255;
  const int rest = idx >> 8;
  const int f = rest & 127;
  const int b = rest >> 7;
  f32x4 q = *(const f32x4*)(Yt + (size_t)f * 32768 + b * 1024 + v3 * 4);
  float mx = fmaxf(fmaxf(q[0], q[1]), fmaxf(q[2], q[3]));
  p2[(size_t)b * 32768 + f * 256 + v3] = mx;
}

// ---------------- FC: out[b][o] = 64 * sum_i p2[b][i]*Wfc[o][i] + bfc[o] ----------------
__global__ __launch_bounds__(256) void k_fc(const float* __restrict__ p2,
                                            const float* __restrict__ Wfc,
                                            const float* __restrict__ bfc,
                                            float* __restrict__ out) {
  const int b = blockIdx.x;
  const int t = threadIdx.x;
  float acc[10];
#pragma unroll
  for (int o = 0; o < 10; ++o) acc[o] = 0.f;
  const float* pb = p2 + (size_t)b * 32768;
  for (int i = t; i < 32768; i += 256) {
    float p = pb[i];
#pragma unroll
    for (int o = 0; o < 10; ++o) acc[o] += p * Wfc[(size_t)o * 32768 + i];
  }
  __shared__ float red[10][256];
#pragma unroll
  for (int o = 0; o < 10; ++o) red[o][t] = acc[o];
  __syncthreads();
  for (int s = 128; s > 0; s >>= 1) {
    if (t < s) {
#pragma unroll
      for (int o = 0; o < 10; ++o) red[o][t] += red[o][t + s];
    }
    __syncthreads();
  }
  if (t < 10) out[b * 10 + t] = 64.f * red[t][0] + bfc[t];
}

extern "C" void kernel_launch(void* const* d_in, const int* in_sizes, int n_in,
                              void* d_out, int out_size, void* d_ws, size_t ws_size,
                              hipStream_t stream) {
  (void)in_sizes; (void)n_in; (void)out_size; (void)ws_size;
  const float* x = (const float*)d_in[0];
  const int* perm = (const int*)d_in[1];
  const float* L1 = (const float*)d_in[2];
  const float* L2 = (const float*)d_in[3];
  const float* W1 = (const float*)d_in[4];
  const float* b1 = (const float*)d_in[5];
  const float* W2 = (const float*)d_in[6];
  const float* b2 = (const float*)d_in[7];
  const float* Wfc = (const float*)d_in[8];
  const float* bfc = (const float*)d_in[9];
  float* out = (float*)d_out;

  char* ws = (char*)d_ws;
  size_t off = 0;
  auto alloc = [&](size_t bytes) {
    char* p = ws + off;
    off += (bytes + 255) & ~(size_t)255;
    return p;
  };
  _Float16* L1h = (_Float16*)alloc(16777216ull * 2);
  _Float16* L2h = (_Float16*)alloc(1048576ull * 2);
  _Float16* W1p = (_Float16*)alloc(64ull * 416 * 2);
  _Float16* W2p = (_Float16*)alloc(128ull * 1664 * 2);
  float* musig = (float*)alloc(32 * 4);
  _Float16* XS = (_Float16*)alloc(25ull * 2097152 * 2);   // states, reused conv1/conv2
  float* Yt = (float*)alloc(64ull * 131072 * 4);          // reused for Yt2
  float* p2 = (float*)alloc(32ull * 128 * 256 * 4);

  k_cvt_f16<<<16384, 256, 0, stream>>>(L1, L1h, 16777216);
  k_cvt_f16<<<1024, 256, 0, stream>>>(L2, L2h, 1048576);
  k_prep_w<<<104, 256, 0, stream>>>(W1, W1p, 64, 4);
  k_prep_w<<<832, 256, 0, stream>>>(W2, W2p, 128, 6);
  k_bn_stats<<<16, 256, 0, stream>>>(x, musig);
  k_build_x0<<<8192, 256, 0, stream>>>(x, perm, musig, XS);

  const size_t plane = 2097152;
  for (int k = 1; k < 25; ++k) {
    k_cheb<<<dim3(64, 8), 256, 0, stream>>>(
        XS + (size_t)(k - 1) * plane, L1h,
        XS + (size_t)(k >= 2 ? k - 2 : 0) * plane, XS + (size_t)k * plane,
        4096, (k == 1) ? 1.f : 2.f, (k == 1) ? 0.f : 1.f);
  }
  k_dense<<<dim3(2048, 1), 256, 0, stream>>>(W1p, XS, b1, Yt, 4096, 4, 13, plane,
                                             131072, 16.f, 1.f);
  k_pool1<<<8192, 256, 0, stream>>>(Yt, XS);
  for (int k = 1; k < 25; ++k) {
    k_cheb<<<dim3(16, 32), 256, 0, stream>>>(
        XS + (size_t)(k - 1) * plane, L2h,
        XS + (size_t)(k >= 2 ? k - 2 : 0) * plane, XS + (size_t)k * plane,
        1024, (k == 1) ? 1.f : 2.f, (k == 1) ? 0.f : 1.f);
  }
  k_dense<<<dim3(512, 2), 256, 0, stream>>>(W2p, XS, b2, Yt, 1024, 6, 52, plane,
                                            32768, 1.f, 0.015625f);
  k_pool2<<<4096, 256, 0, stream>>>(Yt, p2);
  k_fc<<<32, 256, 0, stream>>>(p2, Wfc, bfc, out);
}